// Round 1
// baseline (347.877 us; speedup 1.0000x reference)
//
#include <hip/hip_runtime.h>
#include <hip/hip_fp16.h>

#define NBC 14
#define NAC 45
#define KF  52
#define RHO 0.05f
#define TT  4096
#define BB  64
#define CH  256          // output steps per chunk
#define WU  320          // warmup steps (state forgetting: 0.95^320 ~ 7e-8)
#define NCHUNK 16        // TT / CH
#define NTMAX (CH + WU)  // 576 (multiple of 64)
#define XPAD  (NTMAX + 8)   // xf_lds row stride in halfs (bank-spread)
#define XLN   (NTMAX + KF)  // x slice length incl. halo

__global__ __launch_bounds__(64)
void bcn_kernel(const float* __restrict__ x,
                const float* __restrict__ bck,
                const float* __restrict__ lss,
                const float* __restrict__ soff,
                const float* __restrict__ lbaw,
                const float* __restrict__ ltr,
                const float* __restrict__ ltd,
                const float* __restrict__ lass,
                const float* __restrict__ asoff,
                const float* __restrict__ labw,
                const float* __restrict__ oscale,
                float* __restrict__ out)
{
  __shared__ __half xf_lds[NBC * XPAD];            // conv output (fp16)
  __shared__ float  x_lds[XLN];                    // stimulus slice
  __shared__ float  u_hist[64 * 48];               // ring of u[a] (52-deep window)
  __shared__ __align__(16) float ac_lds[48];       // ac_out broadcast (45 + 3 zero pad)
  __shared__ __align__(16) float rel_lds[16];      // rel broadcast (14 + 2 zero pad)

  const int lid   = threadIdx.x;
  const int blk   = blockIdx.x;
  const int b     = blk >> 4;          // batch
  const int chunk = blk & 15;
  const int t0      = chunk * CH;
  const int t_begin = (chunk == 0) ? 0 : (t0 - WU);
  const int NT      = t0 + CH - t_begin;   // 256 (chunk 0) or 576
  const int warm    = t0 - t_begin;

  // ---- zero-init LDS ----
  for (int i = lid; i < 64 * 48; i += 64) u_hist[i] = 0.f;
  if (lid < 48) ac_lds[lid] = 0.f;
  if (lid < 16) rel_lds[lid] = 0.f;

  // ---- load stimulus slice (with causal zero pad at t<0) ----
  for (int p = lid; p < NT + KF - 1; p += 64) {
    int gt = t_begin - (KF - 1) + p;
    x_lds[p] = (gt >= 0) ? x[b * TT + gt] : 0.f;
  }
  __syncthreads();

  // ---- causal conv into xf_lds (fp16): xf[c][tau] = sum_k bck[c][k] * x[t-51+k] ----
  for (int ib = 0; ib < (NT >> 6); ++ib) {
    int tau = lid + (ib << 6);
    float acc[NBC];
#pragma unroll
    for (int c = 0; c < NBC; ++c) acc[c] = 0.f;
#pragma unroll 4
    for (int k = 0; k < KF; ++k) {
      float xv = x_lds[tau + k];
#pragma unroll
      for (int c = 0; c < NBC; ++c) acc[c] = fmaf(bck[c * KF + k], xv, acc[c]);
    }
#pragma unroll
    for (int c = 0; c < NBC; ++c) xf_lds[c * XPAD + tau] = __float2half(acc[c]);
  }

  // ---- per-lane parameters ----
  float slope_c = 0.f, off_c = 0.f, osc_c = 0.f;
  float pool_b = 1.f, pool_l = 1.f;
  float r1i = 0.f, r2i = 0.f, co1 = 0.f, co2 = 0.f, cn1 = 0.f, cn2 = 0.f;
  float inorm = 0.f, aslope = 0.f, aoff = 0.f;
  float w1r[NBC];
  float w2g[12];
  float S1 = 0.f, S2 = 0.f;
  const int cc = lid & 15, g = lid >> 4;

#pragma unroll
  for (int i = 0; i < NBC; ++i) w1r[i] = 0.f;
#pragma unroll
  for (int i = 0; i < 12; ++i) w2g[i] = 0.f;

  if (lid < NBC) {
    slope_c = expf(lss[lid]);
    off_c   = soff[lid];
    osc_c   = oscale[lid];
  }
  if (lid < NAC) {
    float tr = expf(ltr[lid]);
    float td = expf(ltd[lid]);
    float a1 = 1.f / td;                 // rate of exp(-kt/td)
    float gg = (td + tr) / (td * tr);    // rate of second exponential
    // kt[k] = 0.8 - k/64;  E[k] = exp(-rate*kt[k]) = geometric in k
    r1i = expf(-a1 * 0.015625f);         // per-step decay (advance time)
    r2i = expf(-gg * 0.015625f);
    cn1 = expf(-a1 * 0.003125f);         // E1[51] (newest tap)
    cn2 = expf(-gg * 0.003125f);
    co1 = expf(-a1 * 0.815625f);         // E1[-1] = E1[0]*r1i (tap falling off)
    co2 = expf(-gg * 0.815625f);
    float nrm = 0.f;
    for (int k = 0; k < KF; ++k) {
      float kt = 0.8f - (float)k * 0.015625f;
      float d = expf(-a1 * kt) - expf(-gg * kt);
      nrm = fmaf(d, d, nrm);
    }
    inorm  = 1.f / sqrtf(nrm);
    aslope = expf(lass[lid]);
    aoff   = asoff[lid];
#pragma unroll
    for (int j = 0; j < NBC; ++j) w1r[j] = expf(lbaw[lid * NBC + j]);
  }
  if (cc < NBC) {
#pragma unroll
    for (int j = 0; j < 12; ++j) {
      int a = g * 12 + j;
      w2g[j] = (a < NAC) ? -expf(labw[cc * NAC + a]) : 0.f;
    }
  }

  // ---- output pointers (flat concat: y_bcn, fb, ac_out, y_lnr) ----
  float* yb  = out;
  float* fbp = out + BB * TT * NBC;
  float* acp = out + 2 * BB * TT * NBC;
  float* ylp = out + 2 * BB * TT * NBC + BB * TT * NAC;
  int ob = (b * TT + t0) * NBC + ((lid < NBC) ? lid : 0);
  int oa = (b * TT + t0) * NAC + ((lid < NAC) ? lid : 0);

  __syncthreads();

  // ---- sequential recurrence (wave-synchronous; single wave per block) ----
  for (int s = 0; s < NT; ++s) {
    const bool emit = (s >= warm);

    // AC phase: drive from exponential states, sigmoid, broadcast
    if (lid < NAC) {
      float drive = (S1 - S2) * inorm;
      float z  = aslope * (drive - aoff);
      float ac = __fdividef(1.f, 1.f + __expf(-z));
      ac_lds[lid] = ac;
      if (emit) acp[oa] = ac;
    }
    asm volatile("" ::: "memory");

    // fb = ac_out @ (-exp(labw)).T : 4 groups of 12, xor-reduce over groups
    float4 v0 = *(const float4*)&ac_lds[g * 12];
    float4 v1 = *(const float4*)&ac_lds[g * 12 + 4];
    float4 v2 = *(const float4*)&ac_lds[g * 12 + 8];
    float sA = fmaf(w2g[0],  v0.x, w2g[1]  * v0.y);
    float sB = fmaf(w2g[2],  v0.z, w2g[3]  * v0.w);
    float sC = fmaf(w2g[4],  v1.x, w2g[5]  * v1.y);
    float sD = fmaf(w2g[6],  v1.z, w2g[7]  * v1.w);
    float sE = fmaf(w2g[8],  v2.x, w2g[9]  * v2.y);
    float sF = fmaf(w2g[10], v2.z, w2g[11] * v2.w);
    float fbv = ((sA + sB) + (sC + sD)) + (sE + sF);
    fbv += __shfl_xor(fbv, 16);
    fbv += __shfl_xor(fbv, 32);

    // BC phase: BCN release + (free) LNR branch
    if (lid < NBC) {
      float xfv  = __half2float(xf_lds[lid * XPAD + s]);
      float pz   = slope_c * ((xfv + fbv) - off_c);
      float prob = __fdividef(1.f, 1.f + __expf(-pz));
      float pool2 = fmaf(1.f - RHO, pool_b, RHO);
      float rel  = prob * pool2;
      pool_b = pool2 - rel;
      rel_lds[lid] = rel;

      float lz = slope_c * (xfv - off_c);
      float pl = __fdividef(1.f, 1.f + __expf(-lz));
      float pool2l = fmaf(1.f - RHO, pool_l, RHO);
      float rll = pl * pool2l;
      pool_l = pool2l - rll;

      if (emit) {
        yb[ob]  = osc_c * rel;
        fbp[ob] = fbv;
        ylp[ob] = osc_c * rll;
      }
    }
    asm volatile("" ::: "memory");

    // u phase: u[a] = sum_b w1[a][b]*rel[b]; update exponential states via ring
    if (lid < NAC) {
      float4 q0 = *(const float4*)&rel_lds[0];
      float4 q1 = *(const float4*)&rel_lds[4];
      float4 q2 = *(const float4*)&rel_lds[8];
      float u0 = fmaf(w1r[0],  q0.x, w1r[1]  * q0.y);
      float u1 = fmaf(w1r[2],  q0.z, w1r[3]  * q0.w);
      float u2 = fmaf(w1r[4],  q1.x, w1r[5]  * q1.y);
      float u3 = fmaf(w1r[6],  q1.z, w1r[7]  * q1.w);
      float u4 = fmaf(w1r[8],  q2.x, w1r[9]  * q2.y);
      float u5 = fmaf(w1r[10], q2.z, w1r[11] * q2.w);
      float u6 = fmaf(w1r[12], rel_lds[12], w1r[13] * rel_lds[13]);
      float u  = ((u0 + u1) + (u2 + u3)) + ((u4 + u5) + u6);

      int rs = (s + 12) & 63;                 // slot of u[s-52] (zero if s<52)
      float uold = u_hist[rs * 48 + lid];
      u_hist[(s & 63) * 48 + lid] = u;

      S1 = fmaf(S1, r1i, fmaf(cn1, u, -co1 * uold));
      S2 = fmaf(S2, r2i, fmaf(cn2, u, -co2 * uold));
    }
    if (emit) { ob += NBC; oa += NAC; }
    asm volatile("" ::: "memory");
  }
}

extern "C" void kernel_launch(void* const* d_in, const int* in_sizes, int n_in,
                              void* d_out, int out_size, void* d_ws, size_t ws_size,
                              hipStream_t stream) {
  (void)in_sizes; (void)n_in; (void)d_ws; (void)ws_size; (void)out_size;
  bcn_kernel<<<dim3(BB * NCHUNK), dim3(64), 0, stream>>>(
      (const float*)d_in[0],  // x
      (const float*)d_in[1],  // bc_kernels
      (const float*)d_in[2],  // log_sigmoid_slope
      (const float*)d_in[3],  // sigmoid_offset
      (const float*)d_in[4],  // log_bc_ac_weight
      (const float*)d_in[5],  // log_ac_tau_rise
      (const float*)d_in[6],  // log_ac_tau_decay
      (const float*)d_in[7],  // log_ac_sigmoid_slope
      (const float*)d_in[8],  // ac_sigmoid_offset
      (const float*)d_in[9],  // log_ac_bc_weight
      (const float*)d_in[10], // out_scale
      (float*)d_out);
}

// Round 2
// 244.772 us; speedup vs baseline: 1.4212x; 1.4212x over previous
//
#include <hip/hip_runtime.h>
#include <hip/hip_fp16.h>

#define NBC 14
#define NAC 45
#define KF  52
#define RHO 0.05f
#define TT  4096
#define BB  64
#define CH  128          // output steps per chunk
#define WU  160          // warmup steps (pool contraction <=0.95/step: 0.95^160 ~ 2.7e-4)
#define NCHUNK 32        // TT / CH
#define NTMAX (CH + WU)  // 288
#define XPAD  (NTMAX + 8)   // xf_lds row stride in halfs
#define XLN   (NTMAX + KF)  // x slice length incl. halo

__global__ __launch_bounds__(64)
void bcn_kernel(const float* __restrict__ x,
                const float* __restrict__ bck,
                const float* __restrict__ lss,
                const float* __restrict__ soff,
                const float* __restrict__ lbaw,
                const float* __restrict__ ltr,
                const float* __restrict__ ltd,
                const float* __restrict__ lass,
                const float* __restrict__ asoff,
                const float* __restrict__ labw,
                const float* __restrict__ oscale,
                float* __restrict__ out)
{
  __shared__ __half xf_lds[NBC * XPAD];            // conv output (fp16)      8288 B
  __shared__ float  x_lds[XLN];                    // stimulus slice          1360 B
  __shared__ __half u_hist[64 * 46];               // ring of u[a] (52-delay) 5888 B
  __shared__ __align__(16) float acg[48];          // ac broadcast, 2 groups x 24
  __shared__ __align__(16) float rel_lds[16];      // rel broadcast (14 + pad)
  __shared__ float ac_st[8 * NAC];                 // output staging (8 steps)
  __shared__ float yb_st[8 * NBC];
  __shared__ float fb_st[8 * NBC];
  __shared__ float yl_st[8 * NBC];

  const int lid   = threadIdx.x;
  const int blk   = blockIdx.x;
  const int b     = blk >> 5;          // batch (NCHUNK=32)
  const int chunk = blk & 31;
  const int t0      = chunk * CH;
  const int warm    = (chunk == 0) ? 0 : WU;
  const int t_begin = t0 - warm;
  const int NT      = CH + warm;       // 128 (chunk 0) or 288

  // ---- zero-init LDS ----
  for (int i = lid; i < (64 * 46) / 2; i += 64) ((unsigned int*)u_hist)[i] = 0u;
  if (lid < 48) acg[lid] = 0.f;
  if (lid < 16) rel_lds[lid] = 0.f;

  // ---- load stimulus slice (with causal zero pad at t<0) ----
  for (int p = lid; p < NT + KF - 1; p += 64) {
    int gt = t_begin - (KF - 1) + p;
    x_lds[p] = (gt >= 0) ? x[b * TT + gt] : 0.f;
  }
  __syncthreads();

  // ---- causal conv into xf_lds (fp16) ----
  for (int ib = 0; ib < ((NT + 63) >> 6); ++ib) {
    int tau = lid + (ib << 6);
    if (tau < NT) {
      float acc[NBC];
#pragma unroll
      for (int c = 0; c < NBC; ++c) acc[c] = 0.f;
#pragma unroll 4
      for (int k = 0; k < KF; ++k) {
        float xv = x_lds[tau + k];
#pragma unroll
        for (int c = 0; c < NBC; ++c) acc[c] = fmaf(bck[c * KF + k], xv, acc[c]);
      }
#pragma unroll
      for (int c = 0; c < NBC; ++c) xf_lds[c * XPAD + tau] = __float2half(acc[c]);
    }
  }

  // ---- per-lane parameters ----
  float slope_c = 0.f, off_c = 0.f, osc_c = 0.f;
  float pool_b = 1.f, pool_l = 1.f;
  float r1i = 0.f, r2i = 0.f, co1 = 0.f, co2 = 0.f, cn1 = 0.f, cn2 = 0.f;
  float inorm = 0.f, aslope = 0.f, aoff = 0.f;
  float w1r[NBC];
  float w2g[24];
  float S1 = 0.f, S2 = 0.f;

#pragma unroll
  for (int i = 0; i < NBC; ++i) w1r[i] = 0.f;
#pragma unroll
  for (int i = 0; i < 24; ++i) w2g[i] = 0.f;

  if (lid < NBC) {
    slope_c = expf(lss[lid]);
    off_c   = soff[lid];
    osc_c   = oscale[lid];
  }
  if (lid < NAC) {
    float tr = expf(ltr[lid]);
    float td = expf(ltd[lid]);
    float a1 = 1.f / td;                 // rate of exp(-kt/td)
    float gg = (td + tr) / (td * tr);    // rate of second exponential
    r1i = expf(-a1 * 0.015625f);         // per-step decay
    r2i = expf(-gg * 0.015625f);
    cn1 = expf(-a1 * 0.003125f);         // newest tap weight (kt[51])
    cn2 = expf(-gg * 0.003125f);
    co1 = expf(-a1 * 0.815625f);         // tap falling off (kt[0]+1/64)
    co2 = expf(-gg * 0.815625f);
    float nrm = 0.f;
    for (int k = 0; k < KF; ++k) {
      float kt = 0.8f - (float)k * 0.015625f;
      float d = expf(-a1 * kt) - expf(-gg * kt);
      nrm = fmaf(d, d, nrm);
    }
    inorm  = 1.f / sqrtf(nrm);
    aslope = expf(lass[lid]);
    aoff   = asoff[lid];
#pragma unroll
    for (int j = 0; j < NBC; ++j) w1r[j] = expf(lbaw[lid * NBC + j]);
  }
  if (lid < 32) {
    int c = lid & 15, h = lid >> 4;
    if (c < NBC) {
      int lim = 23 - h;                  // group0: ac[0..22], group1: ac[23..44]
#pragma unroll
      for (int j = 0; j < 23; ++j)
        if (j < lim) w2g[j] = -expf(labw[c * NAC + h * 23 + j]);
    }
  }

  // ---- output pointers (flat concat: y_bcn, fb, ac_out, y_lnr) ----
  float* yb  = out;
  float* fbp = out + (size_t)BB * TT * NBC;
  float* acp = out + 2 * (size_t)BB * TT * NBC;
  float* ylp = out + 2 * (size_t)BB * TT * NBC + (size_t)BB * TT * NAC;

  __syncthreads();

  // ---- sequential recurrence (single wave per block, wave-synchronous) ----
  for (int s = 0; s < NT; ++s) {
    // prefetch (addresses depend only on s; latency hides under AC phase)
    float uold = 0.f, xfv = 0.f;
    if (lid < NAC) uold = __half2float(u_hist[((s + 12) & 63) * 46 + lid]);
    if (lid < NBC) xfv  = __half2float(xf_lds[lid * XPAD + s]);

    // AC phase: drive from exponential states -> sigmoid -> broadcast + stage
    if (lid < NAC) {
      float drive = (S1 - S2) * inorm;
      float z  = aslope * (drive - aoff);
      float ac = __fdividef(1.f, 1.f + __expf(-z));
      acg[(lid < 23) ? lid : (lid + 1)] = ac;   // group1 base = 24
      ac_st[(s & 7) * NAC + lid] = ac;
    }
    asm volatile("" ::: "memory");

    // fb: 2 groups of 23 ACs, single xor-reduce
    float fbv = 0.f;
    if (lid < 32) {
      const float4* ap = (const float4*)&acg[(lid >> 4) * 24];
      float4 v0 = ap[0], v1 = ap[1], v2 = ap[2];
      float4 v3 = ap[3], v4 = ap[4], v5 = ap[5];
      float sA = fmaf(w2g[0],  v0.x, w2g[1]  * v0.y) + fmaf(w2g[2],  v0.z, w2g[3]  * v0.w);
      float sB = fmaf(w2g[4],  v1.x, w2g[5]  * v1.y) + fmaf(w2g[6],  v1.z, w2g[7]  * v1.w);
      float sC = fmaf(w2g[8],  v2.x, w2g[9]  * v2.y) + fmaf(w2g[10], v2.z, w2g[11] * v2.w);
      float sD = fmaf(w2g[12], v3.x, w2g[13] * v3.y) + fmaf(w2g[14], v3.z, w2g[15] * v3.w);
      float sE = fmaf(w2g[16], v4.x, w2g[17] * v4.y) + fmaf(w2g[18], v4.z, w2g[19] * v4.w);
      float sF = fmaf(w2g[20], v5.x, w2g[21] * v5.y) + fmaf(w2g[22], v5.z, w2g[23] * v5.w);
      fbv = ((sA + sB) + (sC + sD)) + (sE + sF);
    }
    fbv += __shfl_xor(fbv, 16);

    // BC phase: BCN release + (free) LNR branch; stage outputs
    if (lid < NBC) {
      float pz   = slope_c * ((xfv + fbv) - off_c);
      float prob = __fdividef(1.f, 1.f + __expf(-pz));
      float pool2 = fmaf(1.f - RHO, pool_b, RHO);
      float rel  = prob * pool2;
      pool_b = pool2 - rel;
      rel_lds[lid] = rel;

      float lz = slope_c * (xfv - off_c);
      float pl = __fdividef(1.f, 1.f + __expf(-lz));
      float pool2l = fmaf(1.f - RHO, pool_l, RHO);
      float rll = pl * pool2l;
      pool_l = pool2l - rll;

      int st = (s & 7) * NBC + lid;
      yb_st[st] = osc_c * rel;
      fb_st[st] = fbv;
      yl_st[st] = osc_c * rll;
    }
    asm volatile("" ::: "memory");

    // u phase: u[a] = sum_c w1[a][c]*rel[c]; exponential-state update
    if (lid < NAC) {
      float4 q0 = *(const float4*)&rel_lds[0];
      float4 q1 = *(const float4*)&rel_lds[4];
      float4 q2 = *(const float4*)&rel_lds[8];
      float u0 = fmaf(w1r[0],  q0.x, w1r[1]  * q0.y);
      float u1 = fmaf(w1r[2],  q0.z, w1r[3]  * q0.w);
      float u2 = fmaf(w1r[4],  q1.x, w1r[5]  * q1.y);
      float u3 = fmaf(w1r[6],  q1.z, w1r[7]  * q1.w);
      float u4 = fmaf(w1r[8],  q2.x, w1r[9]  * q2.y);
      float u5 = fmaf(w1r[10], q2.z, w1r[11] * q2.w);
      float u6 = fmaf(w1r[12], rel_lds[12], w1r[13] * rel_lds[13]);
      float u  = ((u0 + u1) + (u2 + u3)) + ((u4 + u5) + u6);

      u_hist[(s & 63) * 46 + lid] = __float2half(u);
      S1 = fmaf(S1, r1i, fmaf(cn1, u, -co1 * uold));
      S2 = fmaf(S2, r2i, fmaf(cn2, u, -co2 * uold));
    }
    asm volatile("" ::: "memory");

    // flush staged outputs every 8 steps (coalesced, off critical path)
    if ((s & 7) == 7 && (s - 7) >= warm) {
      int tg = t_begin + s - 7;
      size_t ob14 = ((size_t)b * TT + tg) * NBC;
      size_t oa45 = ((size_t)b * TT + tg) * NAC;
#pragma unroll
      for (int i = 0; i < 2; ++i) {
        int idx = lid + (i << 6);
        if (idx < 8 * NBC) {
          yb[ob14 + idx]  = yb_st[idx];
          fbp[ob14 + idx] = fb_st[idx];
          ylp[ob14 + idx] = yl_st[idx];
        }
      }
#pragma unroll
      for (int i = 0; i < 6; ++i) {
        int idx = lid + (i << 6);
        if (idx < 8 * NAC) acp[oa45 + idx] = ac_st[idx];
      }
      asm volatile("" ::: "memory");
    }
  }
}

extern "C" void kernel_launch(void* const* d_in, const int* in_sizes, int n_in,
                              void* d_out, int out_size, void* d_ws, size_t ws_size,
                              hipStream_t stream) {
  (void)in_sizes; (void)n_in; (void)d_ws; (void)ws_size; (void)out_size;
  bcn_kernel<<<dim3(BB * NCHUNK), dim3(64), 0, stream>>>(
      (const float*)d_in[0],  // x
      (const float*)d_in[1],  // bc_kernels
      (const float*)d_in[2],  // log_sigmoid_slope
      (const float*)d_in[3],  // sigmoid_offset
      (const float*)d_in[4],  // log_bc_ac_weight
      (const float*)d_in[5],  // log_ac_tau_rise
      (const float*)d_in[6],  // log_ac_tau_decay
      (const float*)d_in[7],  // log_ac_sigmoid_slope
      (const float*)d_in[8],  // ac_sigmoid_offset
      (const float*)d_in[9],  // log_ac_bc_weight
      (const float*)d_in[10], // out_scale
      (float*)d_out);
}